// Round 1
// baseline (191.033 us; speedup 1.0000x reference)
//
#include <hip/hip_runtime.h>

#define B 8192
#define F 128
#define H 64

typedef __attribute__((ext_vector_type(8))) short bf16x8;
typedef __attribute__((ext_vector_type(4))) float f32x4;

static __device__ __forceinline__ unsigned short f32_to_bf16_rne(float v) {
    unsigned int u = __float_as_uint(v);
    unsigned int r = (u + 0x7FFFu + ((u >> 16) & 1u)) >> 16;
    return (unsigned short)r;
}
static __device__ __forceinline__ float bf16_to_f32(unsigned short h) {
    return __uint_as_float(((unsigned int)h) << 16);
}

// Split-bf16 MFMA NAM.  Layer2 = 3x mfma_f32_16x16x32_bf16 (hh + hl + lh).
// R4: A-operand split is truncation-based Dekker (hi = u&0xFFFF0000 exact in
// bf16, lo = r-hi exact; pack pairs with v_perm).
// R5: W2 hi/lo RNE conversion hoisted into a one-shot prep kernel (was
// redundantly recomputed by all 32 blocks per feature -> ~1000 VALU
// insts/thread, the dominant term behind VALUBusy=52% vs MfmaUtil=21%).
// nam_main loads B-fragments straight to registers from the pre-packed
// workspace (coalesced 16B/lane, table is L2-resident); LDS buffers and
// __syncthreads eliminated.

// ---- one-shot: W2 (F,H,H) f32 -> per-feature hi/lo bf16 B-fragment table ----
// Layout: per feature, 512 slots x 8 bf16; slot = (nt*2+ks)*64 + c + 16*q
// matches the MFMA B-fragment lane mapping used by nam_main.
__global__ __launch_bounds__(256) void nam_prep(
    const float* __restrict__ W2, short* __restrict__ bhi_g,
    short* __restrict__ blo_g)
{
    const int f = blockIdx.x;
    const int tid = threadIdx.x;
    const float* W2f = W2 + (size_t)f * H * H;
    short* bhi = bhi_g + (size_t)f * 4096;
    short* blo = blo_g + (size_t)f * 4096;
#pragma unroll
    for (int t = tid; t < 512; t += 256) {
        const int n = t & 63;          // output hidden index (MFMA n)
        const int g = t >> 6;          // h-group: h = g*8 + jj (MFMA k)
        const int nt = n >> 4, c = n & 15;
        const int ks = g >> 2, q = g & 3;
        const int slot = (nt * 2 + ks) * 64 + c + 16 * q;
        bf16x8 hv, lv;
#pragma unroll
        for (int jj = 0; jj < 8; ++jj) {
            const float wv = W2f[(g * 8 + jj) * H + n];
            const unsigned short hi = f32_to_bf16_rne(wv);
            const unsigned short lo = f32_to_bf16_rne(wv - bf16_to_f32(hi));
            hv[jj] = (short)hi;
            lv[jj] = (short)lo;
        }
        *(bf16x8*)&bhi[slot * 8] = hv;
        *(bf16x8*)&blo[slot * 8] = lv;
    }
}

__global__ __launch_bounds__(256, 4) void nam_main(
    const float* __restrict__ inputs, const float* __restrict__ W1,
    const float* __restrict__ b1, const short* __restrict__ bhi_g,
    const short* __restrict__ blo_g, const float* __restrict__ b2,
    const float* __restrict__ W3, const float* __restrict__ b3,
    float* __restrict__ out, float* __restrict__ fnn_out)
{
    const int tid = threadIdx.x;
    const int f = blockIdx.y;
    const int b0 = blockIdx.x * 256;

    const float* W1f = W1 + f * H;
    const float* b1f = b1 + f * H;
    const float* b2f = b2 + f * H;
    const float* W3f = W3 + f * H;

    const int lane = tid & 63;
    const int w    = tid >> 6;
    const int q    = lane >> 4;   // quad
    const int col  = lane & 15;

    // ---- resident B fragments: coalesced 16B/lane loads from prep table ----
    // slot = (nt*2+ks)*64 + lane -> within a wave each fragment load covers a
    // contiguous 1KB chunk.  Issue first: longest-latency loads.
    const short* bhi_f = bhi_g + (size_t)f * 4096;
    const short* blo_f = blo_g + (size_t)f * 4096;
    bf16x8 bhi[4][2], blo[4][2];
#pragma unroll
    for (int nt = 0; nt < 4; ++nt)
#pragma unroll
        for (int ks = 0; ks < 2; ++ks) {
            const int slot = (nt * 2 + ks) * 64 + lane;
            bhi[nt][ks] = *(const bf16x8*)&bhi_f[slot * 8];
            blo[nt][ks] = *(const bf16x8*)&blo_f[slot * 8];
        }

    // hoist all 4 m-tiles' x gathers (latency overlap with frag loads)
    float x4[4];
#pragma unroll
    for (int mt = 0; mt < 4; ++mt)
        x4[mt] = inputs[(size_t)(b0 + w * 64 + mt * 16 + col) * F + f];

    // per-lane layer-1 weights: k = ks*32 + q*8 + j
    float w1v[16], b1v[16];
#pragma unroll
    for (int ks = 0; ks < 2; ++ks)
#pragma unroll
        for (int j = 0; j < 8; ++j) {
            w1v[ks * 8 + j] = W1f[ks * 32 + q * 8 + j];
            b1v[ks * 8 + j] = b1f[ks * 32 + q * 8 + j];
        }
    float b2v[4], w3v[4];
#pragma unroll
    for (int nt = 0; nt < 4; ++nt) {
        b2v[nt] = b2f[nt * 16 + col];
        w3v[nt] = W3f[nt * 16 + col];
    }
    const float b3f = b3[f];

    // ---- 4 m-tiles of 16 rows per wave ----
#pragma unroll 1
    for (int mt = 0; mt < 4; ++mt) {
        const int rbase = b0 + w * 64 + mt * 16;
        const float x = x4[mt];

        f32x4 acc[4];
#pragma unroll
        for (int nt = 0; nt < 4; ++nt) {
            acc[nt][0] = b2v[nt]; acc[nt][1] = b2v[nt];
            acc[nt][2] = b2v[nt]; acc[nt][3] = b2v[nt];
        }

#pragma unroll
        for (int ks = 0; ks < 2; ++ks) {
            // A-frag: trunc-Dekker split, v_perm pair-packing.
            union { unsigned int u[4]; bf16x8 v; } Ah, Al;
#pragma unroll
            for (int t = 0; t < 4; ++t) {
                const float r0 = fmaxf(fmaf(x, w1v[ks * 8 + 2 * t],     b1v[ks * 8 + 2 * t]),     0.0f);
                const float r1 = fmaxf(fmaf(x, w1v[ks * 8 + 2 * t + 1], b1v[ks * 8 + 2 * t + 1]), 0.0f);
                const unsigned int u0 = __float_as_uint(r0);
                const unsigned int u1 = __float_as_uint(r1);
                const float l0 = r0 - __uint_as_float(u0 & 0xFFFF0000u);
                const float l1 = r1 - __uint_as_float(u1 & 0xFFFF0000u);
                Ah.u[t] = __builtin_amdgcn_perm(u1, u0, 0x07060302);
                Al.u[t] = __builtin_amdgcn_perm(__float_as_uint(l1),
                                                __float_as_uint(l0), 0x07060302);
            }
#pragma unroll
            for (int nt = 0; nt < 4; ++nt) {
                acc[nt] = __builtin_amdgcn_mfma_f32_16x16x32_bf16(Ah.v, bhi[nt][ks], acc[nt], 0, 0, 0);
                acc[nt] = __builtin_amdgcn_mfma_f32_16x16x32_bf16(Ah.v, blo[nt][ks], acc[nt], 0, 0, 0);
                acc[nt] = __builtin_amdgcn_mfma_f32_16x16x32_bf16(Al.v, bhi[nt][ks], acc[nt], 0, 0, 0);
            }
        }

        // ---- epilogue: fnn[row] = sum_n relu(C)*W3[n] + b3; out[row] += fnn ----
        float s[4];
#pragma unroll
        for (int reg = 0; reg < 4; ++reg) {
            float t = 0.0f;
#pragma unroll
            for (int nt = 0; nt < 4; ++nt)
                t = fmaf(fmaxf(acc[nt][reg], 0.0f), w3v[nt], t);
            s[reg] = t;
        }
#pragma unroll
        for (int m_ = 1; m_ <= 8; m_ <<= 1)
#pragma unroll
            for (int reg = 0; reg < 4; ++reg)
                s[reg] += __shfl_xor(s[reg], m_, 64);
        if (col == 0) {
#pragma unroll
            for (int reg = 0; reg < 4; ++reg) {
                const int row = rbase + 4 * q + reg;
                const float val = s[reg] + b3f;
                fnn_out[(size_t)row * F + f] = val;
                atomicAdd(&out[row], val);
            }
        }
    }
}

extern "C" void kernel_launch(void* const* d_in, const int* in_sizes, int n_in,
                              void* d_out, int out_size, void* d_ws, size_t ws_size,
                              hipStream_t stream) {
    const float* inputs = (const float*)d_in[0];
    const float* W1     = (const float*)d_in[1];
    const float* b1     = (const float*)d_in[2];
    const float* W2     = (const float*)d_in[3];
    const float* b2     = (const float*)d_in[4];
    const float* W3     = (const float*)d_in[5];
    const float* b3     = (const float*)d_in[6];

    float* out = (float*)d_out;   // (B,)
    float* fnn = out + B;         // (B, F)

    short* bhi_g = (short*)d_ws;                  // F*512*8 bf16 = 1 MB
    short* blo_g = bhi_g + (size_t)F * 512 * 8;   // 1 MB

    hipMemsetAsync(out, 0, B * sizeof(float), stream);
    nam_prep<<<dim3(F), 256, 0, stream>>>(W2, bhi_g, blo_g);
    nam_main<<<dim3(B / 256, F), 256, 0, stream>>>(inputs, W1, b1, bhi_g, blo_g,
                                                   b2, W3, b3, out, fnn);
}

// Round 3
// 107.458 us; speedup vs baseline: 1.7777x; 1.7777x over previous
//
#include <hip/hip_runtime.h>

#define B 8192
#define F 128
#define H 64

typedef __attribute__((ext_vector_type(8))) short bf16x8;
typedef __attribute__((ext_vector_type(4))) float f32x4;

static __device__ __forceinline__ unsigned short f32_to_bf16_rne(float v) {
    unsigned int u = __float_as_uint(v);
    unsigned int r = (u + 0x7FFFu + ((u >> 16) & 1u)) >> 16;
    return (unsigned short)r;
}
static __device__ __forceinline__ float bf16_to_f32(unsigned short h) {
    return __uint_as_float(((unsigned int)h) << 16);
}

// 16B-wide global->LDS DMA; LDS dest is wave-uniform base + lane*16 (linear).
#define GLOAD_LDS16(gp, lp)                                                  \
    __builtin_amdgcn_global_load_lds(                                        \
        (const __attribute__((address_space(1))) unsigned int*)(gp),         \
        (__attribute__((address_space(3))) unsigned int*)(lp), 16, 0, 0)

// Split-bf16 MFMA NAM.  Layer2 = 3x mfma_f32_16x16x32_bf16 (hh + hl + lh).
// R7 = R6 resubmit (infra failure, no counters) + two fault-hardening fixes:
//   (1) __align__(16) on LDS arrays used with 16B DMA / bf16x8 reads
//       (__shared__ short only guarantees 2B alignment).
//   (2) ws_size guard: full path needs 10MB of d_ws; if the harness gives
//       less, fall back to the proven R4 monolithic kernel (107.7us) so we
//       can never write past the workspace.
// R6 rationale (unchanged): R5's 2.7x regression was memory-system waste:
//   (a) compiler rematerialized global B-fragment loads inside the mt loop
//       (VGPR_Count=64) -> ~241MB FETCH.  Fix: one global_load_lds DMA of
//       the 16KB slice into LDS per block (layout already base+lane*16).
//   (b) inputs[row*F+f] gather = 4B per 512B stride.  Fix: prep transposes
//       inputs -> xT (F,B); gather becomes a fully-used 64B segment.
//   (c) fnn[row*F+f] scatter = 4B per 512B stride RMW.  Fix: main writes
//       fnn_ws (F,B) full-line float4; nam_finish transposes to fnn (B,F)
//       and emits out row-sums (atomics: 1M -> 32K).

// ---- prep: blocks [0,512): inputs->xT transpose; [512,640): W2 table ----
__global__ __launch_bounds__(256) void nam_prep(
    const float* __restrict__ inputs, const float* __restrict__ W2,
    short* __restrict__ bhi_g, short* __restrict__ blo_g,
    float* __restrict__ xT)
{
    const int tid = threadIdx.x;
    const int blk = blockIdx.x;
    __shared__ float tile[32][65];
    if (blk < 512) {
        const int r0 = (blk & 127) * 64;   // 64-row chunk
        const int f0 = (blk >> 7) * 32;    // 32-feature chunk
#pragma unroll
        for (int j = 0; j < 8; ++j) {      // coalesced 128B/32-lane reads
            const int rl = j * 8 + (tid >> 5);
            const int fl = tid & 31;
            tile[fl][rl] = inputs[(size_t)(r0 + rl) * F + f0 + fl];
        }
        __syncthreads();
#pragma unroll
        for (int j = 0; j < 8; ++j) {      // coalesced 256B/64-lane writes
            const int fl = j * 4 + (tid >> 6);
            const int rl = tid & 63;
            xT[(size_t)(f0 + fl) * B + r0 + rl] = tile[fl][rl];
        }
    } else {
        const int f = blk - 512;
        const float* W2f = W2 + (size_t)f * H * H;
        short* bhi = bhi_g + (size_t)f * 4096;
        short* blo = blo_g + (size_t)f * 4096;
#pragma unroll
        for (int t = tid; t < 512; t += 256) {
            const int n = t & 63;          // output hidden index (MFMA n)
            const int g = t >> 6;          // h-group: h = g*8 + jj (MFMA k)
            const int nt = n >> 4, c = n & 15;
            const int ks = g >> 2, q = g & 3;
            const int slot = (nt * 2 + ks) * 64 + c + 16 * q;
            bf16x8 hv, lv;
#pragma unroll
            for (int jj = 0; jj < 8; ++jj) {
                const float wv = W2f[(g * 8 + jj) * H + n];
                const unsigned short hi = f32_to_bf16_rne(wv);
                const unsigned short lo = f32_to_bf16_rne(wv - bf16_to_f32(hi));
                hv[jj] = (short)hi;
                lv[jj] = (short)lo;
            }
            *(bf16x8*)&bhi[slot * 8] = hv;
            *(bf16x8*)&blo[slot * 8] = lv;
        }
    }
}

__global__ __launch_bounds__(256, 3) void nam_main(
    const float* __restrict__ xT, const float* __restrict__ W1,
    const float* __restrict__ b1, const short* __restrict__ bhi_g,
    const short* __restrict__ blo_g, const float* __restrict__ b2,
    const float* __restrict__ W3, const float* __restrict__ b3,
    float* __restrict__ fnn_ws)
{
    const int tid = threadIdx.x;
    const int f = blockIdx.y;
    const int b0 = blockIdx.x * 256;

    const int lane = tid & 63;
    const int w    = tid >> 6;
    const int q    = lane >> 4;   // quad
    const int col  = lane & 15;

    // ---- DMA the pre-packed B-fragment slice into LDS (16KB, once) ----
    __shared__ __align__(16) short bhs[4096];   // 8 KB
    __shared__ __align__(16) short bls[4096];   // 8 KB
    {
        const short* bhi_f = bhi_g + (size_t)f * 4096;
        const short* blo_f = blo_g + (size_t)f * 4096;
#pragma unroll
        for (int c = w; c < 8; c += 4) {      // 2 chunks/table/wave
            GLOAD_LDS16(bhi_f + c * 512 + lane * 8, &bhs[c * 512]);
            GLOAD_LDS16(blo_f + c * 512 + lane * 8, &bls[c * 512]);
        }
    }

    // overlap with DMA: x gathers (coalesced from xT) + per-lane weights
    float x4[4];
#pragma unroll
    for (int mt = 0; mt < 4; ++mt)
        x4[mt] = xT[(size_t)f * B + b0 + w * 64 + mt * 16 + col];

    const float* W1f = W1 + f * H;
    const float* b1f = b1 + f * H;
    float w1v[16], b1v[16];
#pragma unroll
    for (int ks = 0; ks < 2; ++ks)
#pragma unroll
        for (int j = 0; j < 8; ++j) {
            w1v[ks * 8 + j] = W1f[ks * 32 + q * 8 + j];
            b1v[ks * 8 + j] = b1f[ks * 32 + q * 8 + j];
        }
    const float* b2f = b2 + f * H;
    const float* W3f = W3 + f * H;
    float b2v[4], w3v[4];
#pragma unroll
    for (int nt = 0; nt < 4; ++nt) {
        b2v[nt] = b2f[nt * 16 + col];
        w3v[nt] = W3f[nt * 16 + col];
    }
    const float b3f = b3[f];

    __syncthreads();   // drains the global_load_lds DMA

    // ---- resident B fragments (LDS -> regs; re-reads, if any, hit LDS) ----
    bf16x8 bhi[4][2], blo[4][2];
#pragma unroll
    for (int nt = 0; nt < 4; ++nt)
#pragma unroll
        for (int ks = 0; ks < 2; ++ks) {
            const int slot = (nt * 2 + ks) * 64 + lane;
            bhi[nt][ks] = *(bf16x8*)&bhs[slot * 8];
            blo[nt][ks] = *(bf16x8*)&bls[slot * 8];
        }

    // ---- 4 m-tiles of 16 rows per wave ----
#pragma unroll 1
    for (int mt = 0; mt < 4; ++mt) {
        const int rbase = b0 + w * 64 + mt * 16;
        const float x = x4[mt];

        f32x4 acc[4];
#pragma unroll
        for (int nt = 0; nt < 4; ++nt) {
            acc[nt][0] = b2v[nt]; acc[nt][1] = b2v[nt];
            acc[nt][2] = b2v[nt]; acc[nt][3] = b2v[nt];
        }

#pragma unroll
        for (int ks = 0; ks < 2; ++ks) {
            // A-frag: trunc-Dekker split, v_perm pair-packing.
            union { unsigned int u[4]; bf16x8 v; } Ah, Al;
#pragma unroll
            for (int t = 0; t < 4; ++t) {
                const float r0 = fmaxf(fmaf(x, w1v[ks * 8 + 2 * t],     b1v[ks * 8 + 2 * t]),     0.0f);
                const float r1 = fmaxf(fmaf(x, w1v[ks * 8 + 2 * t + 1], b1v[ks * 8 + 2 * t + 1]), 0.0f);
                const unsigned int u0 = __float_as_uint(r0);
                const unsigned int u1 = __float_as_uint(r1);
                const float l0 = r0 - __uint_as_float(u0 & 0xFFFF0000u);
                const float l1 = r1 - __uint_as_float(u1 & 0xFFFF0000u);
                Ah.u[t] = __builtin_amdgcn_perm(u1, u0, 0x07060302);
                Al.u[t] = __builtin_amdgcn_perm(__float_as_uint(l1),
                                                __float_as_uint(l0), 0x07060302);
            }
#pragma unroll
            for (int nt = 0; nt < 4; ++nt) {
                acc[nt] = __builtin_amdgcn_mfma_f32_16x16x32_bf16(Ah.v, bhi[nt][ks], acc[nt], 0, 0, 0);
                acc[nt] = __builtin_amdgcn_mfma_f32_16x16x32_bf16(Ah.v, blo[nt][ks], acc[nt], 0, 0, 0);
                acc[nt] = __builtin_amdgcn_mfma_f32_16x16x32_bf16(Al.v, bhi[nt][ks], acc[nt], 0, 0, 0);
            }
        }

        // ---- epilogue: fnn_ws[f][row] = sum_n relu(C)*W3[n] + b3 ----
        float s[4];
#pragma unroll
        for (int reg = 0; reg < 4; ++reg) {
            float t = 0.0f;
#pragma unroll
            for (int nt = 0; nt < 4; ++nt)
                t = fmaf(fmaxf(acc[nt][reg], 0.0f), w3v[nt], t);
            s[reg] = t;
        }
#pragma unroll
        for (int m_ = 1; m_ <= 8; m_ <<= 1)
#pragma unroll
            for (int reg = 0; reg < 4; ++reg)
                s[reg] += __shfl_xor(s[reg], m_, 64);
        if (col == 0) {
            // rows rbase+4q..rbase+4q+3 consecutive -> one full float4,
            // 4 lanes/wave cover a fully-written 64B line.  No atomics.
            f32x4 o;
            o[0] = s[0] + b3f; o[1] = s[1] + b3f;
            o[2] = s[2] + b3f; o[3] = s[3] + b3f;
            *(f32x4*)&fnn_ws[(size_t)f * B + rbase + 4 * q] = o;
        }
    }
}

// ---- finish: fnn_ws (F,B) -> fnn (B,F) transpose + out row-sums ----
__global__ __launch_bounds__(256) void nam_finish(
    const float* __restrict__ fnn_ws, float* __restrict__ fnn,
    float* __restrict__ out)
{
    const int tid = threadIdx.x;
    const int blk = blockIdx.x;            // 512 blocks: 128 row x 4 f chunks
    const int r0 = (blk & 127) * 64;
    const int f0 = (blk >> 7) * 32;
    __shared__ float tile[32][65];
    __shared__ float psum[4][64];

    float rsum = 0.0f;
#pragma unroll
    for (int j = 0; j < 8; ++j) {          // coalesced 256B/64-lane reads
        const int fl = j * 4 + (tid >> 6);
        const int rl = tid & 63;
        const float v = fnn_ws[(size_t)(f0 + fl) * B + r0 + rl];
        tile[fl][rl] = v;
        rsum += v;
    }
    psum[tid >> 6][tid & 63] = rsum;
    __syncthreads();
    if (tid < 64) {                        // 1 atomic per (row, f-chunk)
        const float s = psum[0][tid] + psum[1][tid] + psum[2][tid] + psum[3][tid];
        atomicAdd(&out[r0 + tid], s);
    }
#pragma unroll
    for (int j = 0; j < 8; ++j) {          // coalesced 128B/32-lane writes
        const int rl = j * 8 + (tid >> 5);
        const int fl = tid & 31;
        fnn[(size_t)(r0 + rl) * F + f0 + fl] = tile[fl][rl];
    }
}

// ---- fallback: proven R4 monolithic kernel (used only if ws too small) ----
__global__ __launch_bounds__(256, 3) void nam_mono(
    const float* __restrict__ inputs, const float* __restrict__ W1,
    const float* __restrict__ b1, const float* __restrict__ W2,
    const float* __restrict__ b2, const float* __restrict__ W3,
    const float* __restrict__ b3, float* __restrict__ out,
    float* __restrict__ fnn_out)
{
    const int tid = threadIdx.x;
    const int f = blockIdx.y;
    const int b0 = blockIdx.x * 256;

    const float* W1f = W1 + f * H;
    const float* b1f = b1 + f * H;
    const float* W2f = W2 + (size_t)f * H * H;
    const float* b2f = b2 + f * H;
    const float* W3f = W3 + f * H;

    __shared__ __align__(16) short bhi_s[512 * 8];
    __shared__ __align__(16) short blo_s[512 * 8];

#pragma unroll
    for (int t = tid; t < 512; t += 256) {
        const int n = t & 63;
        const int g = t >> 6;
        const int nt = n >> 4, c = n & 15;
        const int ks = g >> 2, q = g & 3;
        const int slot = (nt * 2 + ks) * 64 + c + 16 * q;
        bf16x8 hv, lv;
#pragma unroll
        for (int jj = 0; jj < 8; ++jj) {
            const float wv = W2f[(g * 8 + jj) * H + n];
            const unsigned short hi = f32_to_bf16_rne(wv);
            const unsigned short lo = f32_to_bf16_rne(wv - bf16_to_f32(hi));
            hv[jj] = (short)hi;
            lv[jj] = (short)lo;
        }
        *(bf16x8*)&bhi_s[slot * 8] = hv;
        *(bf16x8*)&blo_s[slot * 8] = lv;
    }

    const int lane = tid & 63;
    const int w    = tid >> 6;
    const int q    = lane >> 4;
    const int col  = lane & 15;

    float w1v[16], b1v[16];
#pragma unroll
    for (int ks = 0; ks < 2; ++ks)
#pragma unroll
        for (int j = 0; j < 8; ++j) {
            w1v[ks * 8 + j] = W1f[ks * 32 + q * 8 + j];
            b1v[ks * 8 + j] = b1f[ks * 32 + q * 8 + j];
        }
    float b2v[4], w3v[4];
#pragma unroll
    for (int nt = 0; nt < 4; ++nt) {
        b2v[nt] = b2f[nt * 16 + col];
        w3v[nt] = W3f[nt * 16 + col];
    }
    const float b3f = b3[f];

    float x4[4];
#pragma unroll
    for (int mt = 0; mt < 4; ++mt)
        x4[mt] = inputs[(size_t)(b0 + w * 64 + mt * 16 + col) * F + f];

    __syncthreads();

    bf16x8 bhi[4][2], blo[4][2];
#pragma unroll
    for (int nt = 0; nt < 4; ++nt)
#pragma unroll
        for (int ks = 0; ks < 2; ++ks) {
            const int slot = (nt * 2 + ks) * 64 + lane;
            bhi[nt][ks] = *(bf16x8*)&bhi_s[slot * 8];
            blo[nt][ks] = *(bf16x8*)&blo_s[slot * 8];
        }

#pragma unroll 1
    for (int mt = 0; mt < 4; ++mt) {
        const int rbase = b0 + w * 64 + mt * 16;
        const float x = x4[mt];

        f32x4 acc[4];
#pragma unroll
        for (int nt = 0; nt < 4; ++nt) {
            acc[nt][0] = b2v[nt]; acc[nt][1] = b2v[nt];
            acc[nt][2] = b2v[nt]; acc[nt][3] = b2v[nt];
        }

#pragma unroll
        for (int ks = 0; ks < 2; ++ks) {
            union { unsigned int u[4]; bf16x8 v; } Ah, Al;
#pragma unroll
            for (int t = 0; t < 4; ++t) {
                const float r0 = fmaxf(fmaf(x, w1v[ks * 8 + 2 * t],     b1v[ks * 8 + 2 * t]),     0.0f);
                const float r1 = fmaxf(fmaf(x, w1v[ks * 8 + 2 * t + 1], b1v[ks * 8 + 2 * t + 1]), 0.0f);
                const unsigned int u0 = __float_as_uint(r0);
                const unsigned int u1 = __float_as_uint(r1);
                const float l0 = r0 - __uint_as_float(u0 & 0xFFFF0000u);
                const float l1 = r1 - __uint_as_float(u1 & 0xFFFF0000u);
                Ah.u[t] = __builtin_amdgcn_perm(u1, u0, 0x07060302);
                Al.u[t] = __builtin_amdgcn_perm(__float_as_uint(l1),
                                                __float_as_uint(l0), 0x07060302);
            }
#pragma unroll
            for (int nt = 0; nt < 4; ++nt) {
                acc[nt] = __builtin_amdgcn_mfma_f32_16x16x32_bf16(Ah.v, bhi[nt][ks], acc[nt], 0, 0, 0);
                acc[nt] = __builtin_amdgcn_mfma_f32_16x16x32_bf16(Ah.v, blo[nt][ks], acc[nt], 0, 0, 0);
                acc[nt] = __builtin_amdgcn_mfma_f32_16x16x32_bf16(Al.v, bhi[nt][ks], acc[nt], 0, 0, 0);
            }
        }

        float s[4];
#pragma unroll
        for (int reg = 0; reg < 4; ++reg) {
            float t = 0.0f;
#pragma unroll
            for (int nt = 0; nt < 4; ++nt)
                t = fmaf(fmaxf(acc[nt][reg], 0.0f), w3v[nt], t);
            s[reg] = t;
        }
#pragma unroll
        for (int m_ = 1; m_ <= 8; m_ <<= 1)
#pragma unroll
            for (int reg = 0; reg < 4; ++reg)
                s[reg] += __shfl_xor(s[reg], m_, 64);
        if (col == 0) {
#pragma unroll
            for (int reg = 0; reg < 4; ++reg) {
                const int row = rbase + 4 * q + reg;
                const float val = s[reg] + b3f;
                fnn_out[(size_t)row * F + f] = val;
                atomicAdd(&out[row], val);
            }
        }
    }
}

extern "C" void kernel_launch(void* const* d_in, const int* in_sizes, int n_in,
                              void* d_out, int out_size, void* d_ws, size_t ws_size,
                              hipStream_t stream) {
    const float* inputs = (const float*)d_in[0];
    const float* W1     = (const float*)d_in[1];
    const float* b1     = (const float*)d_in[2];
    const float* W2     = (const float*)d_in[3];
    const float* b2     = (const float*)d_in[4];
    const float* W3     = (const float*)d_in[5];
    const float* b3     = (const float*)d_in[6];

    float* out = (float*)d_out;   // (B,)
    float* fnn = out + B;         // (B, F)

    const size_t WS_NEEDED = (size_t)F * 4096 * 2 * sizeof(short)   // tables 2MB
                           + (size_t)F * B * 2 * sizeof(float);     // xT+fnw 8MB

    hipMemsetAsync(out, 0, B * sizeof(float), stream);

    if (ws_size >= WS_NEEDED) {
        short* bhi_g = (short*)d_ws;                        // 1 MB
        short* blo_g = bhi_g + (size_t)F * 4096;            // 1 MB
        float* xT    = (float*)(blo_g + (size_t)F * 4096);  // 4 MB  (F, B)
        float* fnw   = xT + (size_t)F * B;                  // 4 MB  (F, B)

        nam_prep<<<dim3(512 + F), 256, 0, stream>>>(inputs, W2, bhi_g, blo_g, xT);
        nam_main<<<dim3(B / 256, F), 256, 0, stream>>>(xT, W1, b1, bhi_g, blo_g,
                                                       b2, W3, b3, fnw);
        nam_finish<<<dim3(512), 256, 0, stream>>>(fnw, fnn, out);
    } else {
        nam_mono<<<dim3(B / 256, F), 256, 0, stream>>>(inputs, W1, b1, W2, b2,
                                                       W3, b3, out, fnn);
    }
}